// Round 2
// baseline (128.135 us; speedup 1.0000x reference)
//
#include <hip/hip_runtime.h>

// Problem dims
constexpr int N_   = 256;
constexpr int T_   = 2048;
constexpr int V_   = 9;
constexpr int COUT_= 3;
constexpr int K_   = 5;
constexpr int KT_  = 9;
constexpr int FIN_ = V_ * 16;     // 144
constexpr int J_   = V_ * COUT_;  // 27 (j = w*3 + o)
constexpr int THREADS_ = 256;
constexpr int TILE_ = THREADS_ - (KT_ - 1);          // 248 output rows per block
constexpr int NTILE_ = (T_ + TILE_ - 1) / TILE_;     // 9
constexpr int CS_ = 17;                              // chunk LDS stride (odd -> conflict-free)
constexpr int ZS_ = 29;                              // z LDS stride (odd -> conflict-free)
constexpr int SMEM_FLOATS = THREADS_ * ZS_;          // 7424 floats = 29696 B

// ws layout (floats)
constexpr int WC_OFF = 0;               // Wc[f][j], 144*27 = 3888
constexpr int B0_OFF = FIN_ * J_;       // 3888, B0[j], 27
constexpr int WT_OFF = B0_OFF + J_;     // 3915, Wt[o][o2][dd], 81
constexpr int BT_OFF = WT_OFF + 81;     // 3996, b_tcn, 3

__global__ void setup_weights(const float* __restrict__ A,
                              const float* __restrict__ Wg,
                              const float* __restrict__ bg,
                              const float* __restrict__ Wt_in,
                              const float* __restrict__ bt,
                              float* __restrict__ ws) {
    const int tid = threadIdx.x;
    // Wc[f=(v*16+c)][j=(w*3+o)] = sum_k Wg[k,o,c] * A[k,v,w]
    for (int idx = tid; idx < FIN_ * J_; idx += blockDim.x) {
        const int f = idx / J_, j = idx % J_;
        const int v = f >> 4, c = f & 15;
        const int w = j / 3, o = j % 3;
        float s = 0.f;
        #pragma unroll
        for (int k = 0; k < K_; ++k)
            s += Wg[(k * 3 + o) * 16 + c] * A[(k * 9 + v) * 9 + w];
        ws[WC_OFF + idx] = s;
    }
    // B0[j] = sum_k bg[k,o] * sum_v A[k,v,w]
    if (tid < J_) {
        const int w = tid / 3, o = tid % 3;
        float s = 0.f;
        #pragma unroll
        for (int k = 0; k < K_; ++k) {
            float cs = 0.f;
            #pragma unroll
            for (int v = 0; v < V_; ++v) cs += A[(k * 9 + v) * 9 + w];
            s += bg[k * 3 + o] * cs;
        }
        ws[B0_OFF + tid] = s;
    }
    // Wt[o][o2][dd] = W_tcn[(o2*3 + o)*9 + (8 - dd)]
    if (tid < 81) {
        const int o = tid / 27, r = tid % 27, o2 = r / 9, dd = r % 9;
        ws[WT_OFF + tid] = Wt_in[(o2 * 3 + o) * 9 + (8 - dd)];
    }
    if (tid < 3) ws[BT_OFF + tid] = bt[tid];
}

__global__ __launch_bounds__(THREADS_) void fused_stgcn(const float* __restrict__ pose,
                                                        const float* __restrict__ cw,
                                                        float* __restrict__ out) {
    __shared__ float smem[SMEM_FLOATS];   // stage1: chunk[256][17]; then z[256][29]; then repack

    const int tid  = threadIdx.x;
    const int bid  = blockIdx.x;
    const int n    = bid / NTILE_;
    const int tile = bid % NTILE_;
    const int t0   = tile * TILE_;

    // ---- Stage 1: z[row] = pose_row(144) x Wc(144x27) + B0, via chunked coalesced LDS staging
    // Loader mapping: fidx = q*256+tid -> row = fidx/4 (q*64 + tid/4), c4 = fidx%4
    const int l_row = (tid >> 2);       // + q*64
    const int l_c4  = (tid & 3);
    const float* gptr[4];
    bool gvalid[4];
    #pragma unroll
    for (int q = 0; q < 4; ++q) {
        const int row  = q * 64 + l_row;
        const int text = t0 - 4 + row;
        gvalid[q] = (text >= 0 && text < T_);
        gptr[q]   = pose + ((size_t)n * T_ + (gvalid[q] ? text : 0)) * FIN_ + l_c4 * 4;
    }

    float4 ld[4];
    #pragma unroll
    for (int q = 0; q < 4; ++q)
        ld[q] = gvalid[q] ? *(const float4*)(gptr[q]) : make_float4(0.f, 0.f, 0.f, 0.f);

    float acc[J_];
    #pragma unroll
    for (int j = 0; j < J_; ++j) acc[j] = cw[B0_OFF + j];

    const float* zc = &smem[tid * CS_];
    #pragma unroll 1
    for (int v9 = 0; v9 < V_; ++v9) {
        __syncthreads();   // previous chunk's reads complete
        #pragma unroll
        for (int q = 0; q < 4; ++q) {
            float* p = &smem[(q * 64 + l_row) * CS_ + l_c4 * 4];
            p[0] = ld[q].x; p[1] = ld[q].y; p[2] = ld[q].z; p[3] = ld[q].w;
        }
        __syncthreads();
        if (v9 < V_ - 1) {
            const int off = (v9 + 1) * 16;
            #pragma unroll
            for (int q = 0; q < 4; ++q)
                ld[q] = gvalid[q] ? *(const float4*)(gptr[q] + off)
                                  : make_float4(0.f, 0.f, 0.f, 0.f);
        }
        const float* wrow = cw + WC_OFF + (v9 * 16) * J_;
        #pragma unroll
        for (int c = 0; c < 16; ++c) {
            const float xv = zc[c];
            #pragma unroll
            for (int j = 0; j < J_; ++j)
                acc[j] = fmaf(xv, wrow[c * J_ + j], acc[j]);
        }
    }

    __syncthreads();   // chunk reads done; reuse smem as zbuf
    {
        const int text = t0 - 4 + tid;
        const bool inr = (text >= 0 && text < T_);
        #pragma unroll
        for (int j = 0; j < J_; ++j) smem[tid * ZS_ + j] = inr ? acc[j] : 0.f;
    }
    __syncthreads();

    // ---- Stage 2: temporal 9-tap mix + bias + leaky relu
    const int rows_out = min(TILE_, T_ - t0);
    float oacc[J_];
    if (tid < rows_out) {
        #pragma unroll
        for (int w = 0; w < V_; ++w)
            #pragma unroll
            for (int o2 = 0; o2 < 3; ++o2)
                oacc[w * 3 + o2] = cw[BT_OFF + o2];
        #pragma unroll
        for (int dd = 0; dd < KT_; ++dd) {
            float zr[J_];
            const float* zp = &smem[(tid + dd) * ZS_];
            #pragma unroll
            for (int j = 0; j < J_; ++j) zr[j] = zp[j];
            #pragma unroll
            for (int o = 0; o < 3; ++o) {
                #pragma unroll
                for (int o2 = 0; o2 < 3; ++o2) {
                    const float wv = cw[WT_OFF + o * 27 + o2 * 9 + dd];
                    #pragma unroll
                    for (int w = 0; w < V_; ++w)
                        oacc[w * 3 + o2] = fmaf(zr[w * 3 + o], wv, oacc[w * 3 + o2]);
                }
            }
        }
        #pragma unroll
        for (int j = 0; j < J_; ++j) oacc[j] = fmaxf(oacc[j], 0.01f * oacc[j]);
    }
    __syncthreads();
    // repack tightly (stride 27) for coalesced copy-out
    if (tid < rows_out) {
        #pragma unroll
        for (int j = 0; j < J_; ++j) smem[tid * J_ + j] = oacc[j];
    }
    __syncthreads();

    const int total4 = (rows_out * J_) / 4;  // 248*27/4=1674, 64*27/4=432
    float4* dst4 = (float4*)(out + ((size_t)n * T_ + t0) * J_);
    const float4* src4 = (const float4*)smem;
    for (int idx = tid; idx < total4; idx += THREADS_)
        dst4[idx] = src4[idx];
}

extern "C" void kernel_launch(void* const* d_in, const int* in_sizes, int n_in,
                              void* d_out, int out_size, void* d_ws, size_t ws_size,
                              hipStream_t stream) {
    const float* pose = (const float*)d_in[0];
    const float* A    = (const float*)d_in[1];
    const float* Wg   = (const float*)d_in[2];
    const float* bg   = (const float*)d_in[3];
    const float* Wt   = (const float*)d_in[4];
    const float* bt   = (const float*)d_in[5];
    float* ws   = (float*)d_ws;
    float* outp = (float*)d_out;

    setup_weights<<<1, 256, 0, stream>>>(A, Wg, bg, Wt, bt, ws);
    fused_stgcn<<<N_ * NTILE_, THREADS_, 0, stream>>>(pose, ws, outp);
}

// Round 3
// 90.251 us; speedup vs baseline: 1.4198x; 1.4198x over previous
//
#include <hip/hip_runtime.h>

typedef short short8 __attribute__((ext_vector_type(8)));
typedef float f32x4  __attribute__((ext_vector_type(4)));

// Problem dims
constexpr int N_    = 256;
constexpr int T_    = 2048;
constexpr int V_    = 9;
constexpr int FIN_  = 144;      // K dim of stage-1 GEMM
constexpr int J_    = 27;       // output cols (w*3 + o)
constexpr int KT_   = 9;
constexpr int THREADS_ = 256;
constexpr int TILE_ = 248;                       // output rows per block
constexpr int NTILE_ = 9;                        // ceil(2048/248)
constexpr int ZROWS_ = 256;                      // z rows per block (TILE_+8)
constexpr int XROWS_ = 64;                       // staged rows per phase
constexpr int XSTRIDE_B = 384;                   // 24 x 16B blocks (192 bf16; K padded 144->160, rest zero)
constexpr int XBUF_B = XROWS_ * XSTRIDE_B;       // 24576 B
constexpr int ZS_ = 28;                          // z row stride in floats (112B, 16B aligned)
constexpr int ZBUF_B = ZROWS_ * ZS_ * 4;         // 28672 B
// total smem = 53248 B

// ws layout (float units)
constexpr int BF_OFF_F = 0;      // B-frags: 5120 bf16 (2560 floats): [((s*2+nt)*64+lane)*8 + e]
constexpr int B0_OFF   = 2560;   // B0[27]
constexpr int WT_OFF   = 2587;   // Wt[o][o2][dd] flattened o*27+o2*9+dd (81)
constexpr int BT_OFF   = 2668;   // b_tcn[3]

__device__ __forceinline__ unsigned short bf16_rne(float x) {
    unsigned u = __float_as_uint(x);
    u = (u + 0x7FFFu + ((u >> 16) & 1u)) >> 16;
    return (unsigned short)u;
}
__device__ __forceinline__ unsigned pk2(float a, float b) {
    return (unsigned)bf16_rne(a) | ((unsigned)bf16_rne(b) << 16);
}

__global__ void setup_weights(const float* __restrict__ A,
                              const float* __restrict__ Wg,
                              const float* __restrict__ bg,
                              const float* __restrict__ Wt_in,
                              const float* __restrict__ bt,
                              float* __restrict__ ws) {
    __shared__ float Wc[FIN_ * J_];   // [k=f][n=j]
    const int tid = threadIdx.x;
    for (int idx = tid; idx < FIN_ * J_; idx += 256) {
        const int f = idx / J_, j = idx % J_;
        const int v = f >> 4, c = f & 15;
        const int w = j / 3, o = j % 3;
        float s = 0.f;
        #pragma unroll
        for (int k = 0; k < 5; ++k)
            s += Wg[(k * 3 + o) * 16 + c] * A[(k * 9 + v) * 9 + w];
        Wc[idx] = s;
    }
    __syncthreads();
    // B-fragments for mfma_f32_16x16x32_bf16: elem e of lane holds (k=s*32+(l>>4)*8+e, n=nt*16+(l&15))
    unsigned short* bfp = (unsigned short*)(ws + BF_OFF_F);
    for (int i = tid; i < 5120; i += 256) {
        const int e = i & 7, lane = (i >> 3) & 63, nt = (i >> 9) & 1, s = i >> 10;
        const int k = s * 32 + (lane >> 4) * 8 + e;
        const int n = nt * 16 + (lane & 15);
        const float val = (k < FIN_ && n < J_) ? Wc[k * J_ + n] : 0.f;
        bfp[i] = bf16_rne(val);
    }
    // B0[j] = sum_k bg[k,o] * sum_v A[k,v,w]
    if (tid < J_) {
        const int w = tid / 3, o = tid % 3;
        float s = 0.f;
        #pragma unroll
        for (int k = 0; k < 5; ++k) {
            float cs = 0.f;
            #pragma unroll
            for (int v = 0; v < V_; ++v) cs += A[(k * 9 + v) * 9 + w];
            s += bg[k * 3 + o] * cs;
        }
        ws[B0_OFF + tid] = s;
    }
    // Wt[o][o2][dd] = W_tcn[(o2*3+o)*9 + (8-dd)]  (conv_transpose: flip + I/O swap)
    if (tid < 81) {
        const int o = tid / 27, r = tid % 27, o2 = r / 9, dd = r % 9;
        ws[WT_OFF + tid] = Wt_in[(o2 * 3 + o) * 9 + (8 - dd)];
    }
    if (tid < 3) ws[BT_OFF + tid] = bt[tid];
}

__global__ __launch_bounds__(THREADS_) void fused_stgcn(const float* __restrict__ pose,
                                                        const float* __restrict__ cw,
                                                        float* __restrict__ out) {
    __shared__ __align__(16) unsigned char smem[XBUF_B + ZBUF_B];
    float* zbuf = (float*)(smem + XBUF_B);

    const int tid  = threadIdx.x;
    const int bid  = blockIdx.x;
    const int nb   = bid / NTILE_;
    const int tile = bid % NTILE_;
    const int t0   = tile * TILE_;
    const int lane = tid & 63;
    const int wv   = tid >> 6;

    // zero xbuf once (pad blocks must stay zero; staging writes are row-bijective)
    {
        f32x4 z4 = {0.f, 0.f, 0.f, 0.f};
        f32x4* p = (f32x4*)smem;
        for (int i = tid; i < XBUF_B / 16; i += THREADS_) p[i] = z4;
    }
    // B-fragments -> registers (40 VGPRs), coalesced 16B loads
    short8 bfrag[5][2];
    {
        const short8* bsrc = (const short8*)(cw + BF_OFF_F);
        #pragma unroll
        for (int s = 0; s < 5; ++s)
            #pragma unroll
            for (int nt = 0; nt < 2; ++nt)
                bfrag[s][nt] = bsrc[(s * 2 + nt) * 64 + lane];
    }
    float b0n0 = cw[B0_OFF + (lane & 15)];
    float b0n1 = (16 + (lane & 15) < J_) ? cw[B0_OFF + 16 + (lane & 15)] : 0.f;
    __syncthreads();

    // ---------------- Stage 1: 4 phases of 64 rows; MFMA 16x16x32 bf16 ----------------
    for (int h = 0; h < 4; ++h) {
        // coalesced load of 64 rows x 144 floats (linear in g), convert, swizzled LDS write
        float4 ld[9];
        #pragma unroll
        for (int q = 0; q < 9; ++q) {
            const int g = q * THREADS_ + tid;
            const int r = g / 36;
            const int c4 = g % 36;
            const int text = t0 - 4 + h * 64 + r;
            const bool ok = (text >= 0 && text < T_);
            ld[q] = ok ? *(const float4*)(pose + ((size_t)nb * T_ + text) * FIN_ + c4 * 4)
                       : make_float4(0.f, 0.f, 0.f, 0.f);
        }
        #pragma unroll
        for (int q = 0; q < 9; ++q) {
            const int g = q * THREADS_ + tid;
            const int r = g / 36;
            const int c4 = g % 36;
            const int blk = (c4 >> 1) ^ (r & 7);          // 16B-block XOR swizzle
            uint2 u;
            u.x = pk2(ld[q].x, ld[q].y);
            u.y = pk2(ld[q].z, ld[q].w);
            *(uint2*)(smem + r * XSTRIDE_B + blk * 16 + (c4 & 1) * 8) = u;
        }
        __syncthreads();

        // each wave computes one 16-row M-tile of this 64-row phase
        f32x4 acc0 = {0.f, 0.f, 0.f, 0.f};
        f32x4 acc1 = {0.f, 0.f, 0.f, 0.f};
        const int arow = wv * 16 + (lane & 15);
        const int g8   = lane >> 4;
        #pragma unroll
        for (int s = 0; s < 5; ++s) {
            const int blk = (s * 4 + g8) ^ (arow & 7);
            short8 afrag = *(const short8*)(smem + arow * XSTRIDE_B + blk * 16);
            acc0 = __builtin_amdgcn_mfma_f32_16x16x32_bf16(afrag, bfrag[s][0], acc0, 0, 0, 0);
            acc1 = __builtin_amdgcn_mfma_f32_16x16x32_bf16(afrag, bfrag[s][1], acc1, 0, 0, 0);
        }
        // D layout: col = lane&15, row = (lane>>4)*4 + reg  [m89-verified]
        #pragma unroll
        for (int r = 0; r < 4; ++r) {
            const int zrow = h * 64 + wv * 16 + g8 * 4 + r;
            const int text = t0 - 4 + zrow;
            const bool ok = (text >= 0 && text < T_);
            const int j0 = lane & 15;
            zbuf[zrow * ZS_ + j0] = ok ? acc0[r] + b0n0 : 0.f;
            if (16 + j0 < J_)
                zbuf[zrow * ZS_ + 16 + j0] = ok ? acc1[r] + b0n1 : 0.f;
        }
        __syncthreads();
    }

    // ---------------- Stage 2: temporal 9-tap mix + bias + leaky relu ----------------
    const int rows_out = min(TILE_, T_ - t0);
    float oacc[J_];
    if (tid < rows_out) {
        #pragma unroll
        for (int w = 0; w < V_; ++w)
            #pragma unroll
            for (int o2 = 0; o2 < 3; ++o2)
                oacc[w * 3 + o2] = cw[BT_OFF + o2];
        #pragma unroll
        for (int dd = 0; dd < KT_; ++dd) {
            union { f32x4 v4[7]; float f[28]; } zu;
            const f32x4* zp = (const f32x4*)&zbuf[(tid + dd) * ZS_];
            #pragma unroll
            for (int c = 0; c < 7; ++c) zu.v4[c] = zp[c];
            #pragma unroll
            for (int o = 0; o < 3; ++o) {
                #pragma unroll
                for (int o2 = 0; o2 < 3; ++o2) {
                    const float wt = cw[WT_OFF + o * 27 + o2 * 9 + dd];
                    #pragma unroll
                    for (int w = 0; w < V_; ++w)
                        oacc[w * 3 + o2] = fmaf(zu.f[w * 3 + o], wt, oacc[w * 3 + o2]);
                }
            }
        }
        #pragma unroll
        for (int j = 0; j < J_; ++j) oacc[j] = fmaxf(oacc[j], 0.01f * oacc[j]);
    }
    __syncthreads();
    // repack tight (stride 27) into zbuf region for coalesced store
    if (tid < rows_out) {
        #pragma unroll
        for (int j = 0; j < J_; ++j) zbuf[tid * J_ + j] = oacc[j];
    }
    __syncthreads();

    const int total4 = (rows_out * J_) / 4;   // 1674 or 432
    float4* dst4 = (float4*)(out + ((size_t)nb * T_ + t0) * J_);
    const float4* src4 = (const float4*)zbuf;
    for (int idx = tid; idx < total4; idx += THREADS_)
        dst4[idx] = src4[idx];
}

extern "C" void kernel_launch(void* const* d_in, const int* in_sizes, int n_in,
                              void* d_out, int out_size, void* d_ws, size_t ws_size,
                              hipStream_t stream) {
    const float* pose = (const float*)d_in[0];
    const float* A    = (const float*)d_in[1];
    const float* Wg   = (const float*)d_in[2];
    const float* bg   = (const float*)d_in[3];
    const float* Wt   = (const float*)d_in[4];
    const float* bt   = (const float*)d_in[5];
    float* ws   = (float*)d_ws;
    float* outp = (float*)d_out;

    setup_weights<<<1, 256, 0, stream>>>(A, Wg, bg, Wt, bt, ws);
    fused_stgcn<<<N_ * NTILE_, THREADS_, 0, stream>>>(pose, ws, outp);
}

// Round 4
// 87.236 us; speedup vs baseline: 1.4688x; 1.0346x over previous
//
#include <hip/hip_runtime.h>

typedef short short8 __attribute__((ext_vector_type(8)));
typedef float f32x4  __attribute__((ext_vector_type(4)));

// Problem dims
constexpr int N_    = 256;
constexpr int T_    = 2048;
constexpr int V_    = 9;
constexpr int FIN_  = 144;      // K dim of stage-1 GEMM
constexpr int J_    = 27;       // output cols (w*3 + o)
constexpr int KT_   = 9;
constexpr int THREADS_ = 256;
constexpr int TILE_ = 248;                       // output rows per block
constexpr int NTILE_ = 9;                        // ceil(2048/248)
constexpr int ZROWS_ = 256;                      // z rows per block (TILE_+8)
constexpr int ZS_ = 28;                          // z row stride floats (28*4=112B; 8-lane bank period covers all 32 banks -> b128 conflict-free)
constexpr int ZBUF_B = ZROWS_ * ZS_ * 4;         // 28672 B total LDS

// ws layout (float units)
constexpr int BF_OFF_F = 0;      // B-frags: 5120 bf16 (2560 floats): [((s*2+nt)*64+lane)*8 + e]
constexpr int B0_OFF   = 2560;   // B0[27]
constexpr int WT_OFF   = 2587;   // Wt[o][o2][dd] flattened o*27+o2*9+dd (81)
constexpr int BT_OFF   = 2668;   // b_tcn[3]

__device__ __forceinline__ unsigned short bf16_rne(float x) {
    unsigned u = __float_as_uint(x);
    u = (u + 0x7FFFu + ((u >> 16) & 1u)) >> 16;
    return (unsigned short)u;
}
__device__ __forceinline__ unsigned pk2(float a, float b) {
    return (unsigned)bf16_rne(a) | ((unsigned)bf16_rne(b) << 16);
}

__global__ void setup_weights(const float* __restrict__ A,
                              const float* __restrict__ Wg,
                              const float* __restrict__ bg,
                              const float* __restrict__ Wt_in,
                              const float* __restrict__ bt,
                              float* __restrict__ ws) {
    __shared__ float Wc[FIN_ * J_];   // [k=f][n=j]
    const int tid = threadIdx.x;
    for (int idx = tid; idx < FIN_ * J_; idx += 256) {
        const int f = idx / J_, j = idx % J_;
        const int v = f >> 4, c = f & 15;
        const int w = j / 3, o = j % 3;
        float s = 0.f;
        #pragma unroll
        for (int k = 0; k < 5; ++k)
            s += Wg[(k * 3 + o) * 16 + c] * A[(k * 9 + v) * 9 + w];
        Wc[idx] = s;
    }
    __syncthreads();
    // B-fragments for mfma_f32_16x16x32_bf16: elem e of lane holds (k=s*32+(l>>4)*8+e, n=nt*16+(l&15))
    unsigned short* bfp = (unsigned short*)(ws + BF_OFF_F);
    for (int i = tid; i < 5120; i += 256) {
        const int e = i & 7, lane = (i >> 3) & 63, nt = (i >> 9) & 1, s = i >> 10;
        const int k = s * 32 + (lane >> 4) * 8 + e;
        const int n = nt * 16 + (lane & 15);
        const float val = (k < FIN_ && n < J_) ? Wc[k * J_ + n] : 0.f;
        bfp[i] = bf16_rne(val);
    }
    // B0[j] = sum_k bg[k,o] * sum_v A[k,v,w]
    if (tid < J_) {
        const int w = tid / 3, o = tid % 3;
        float s = 0.f;
        #pragma unroll
        for (int k = 0; k < 5; ++k) {
            float cs = 0.f;
            #pragma unroll
            for (int v = 0; v < V_; ++v) cs += A[(k * 9 + v) * 9 + w];
            s += bg[k * 3 + o] * cs;
        }
        ws[B0_OFF + tid] = s;
    }
    // Wt[o][o2][dd] = W_tcn[(o2*3+o)*9 + (8-dd)]  (conv_transpose: flip + I/O swap)
    if (tid < 81) {
        const int o = tid / 27, r = tid % 27, o2 = r / 9, dd = r % 9;
        ws[WT_OFF + tid] = Wt_in[(o2 * 3 + o) * 9 + (8 - dd)];
    }
    if (tid < 3) ws[BT_OFF + tid] = bt[tid];
}

__global__ __launch_bounds__(THREADS_) void fused_stgcn(const float* __restrict__ pose,
                                                        const float* __restrict__ cw,
                                                        float* __restrict__ out) {
    __shared__ __align__(16) float zbuf[ZROWS_ * ZS_];   // 28672 B

    const int tid  = threadIdx.x;
    const int bid  = blockIdx.x;
    const int nb   = bid / NTILE_;
    const int tile = bid % NTILE_;
    const int t0   = tile * TILE_;
    const int lane = tid & 63;
    const int wv   = tid >> 6;
    const int g8   = lane >> 4;
    const int j0   = lane & 15;

    // B-fragments -> registers (40 VGPRs), coalesced 16B loads
    short8 bfrag[5][2];
    {
        const short8* bsrc = (const short8*)(cw + BF_OFF_F);
        #pragma unroll
        for (int s = 0; s < 5; ++s)
            #pragma unroll
            for (int nt = 0; nt < 2; ++nt)
                bfrag[s][nt] = bsrc[(s * 2 + nt) * 64 + lane];
    }
    const float b0n0 = cw[B0_OFF + j0];
    const float b0n1 = (j0 < 11) ? cw[B0_OFF + 16 + j0] : 0.f;

    // ---- Stage 1: per-wave independent; direct global->reg A-frags; 4 M-tiles of 16 rows ----
    // A-frag (16x16x32 bf16): lane holds row (lane&15), k = s*32 + g8*8 + e  (e=0..7)
    const size_t nrow0 = (size_t)nb * T_;

    float4 pA[5], pB[5];
    auto issue = [&](int mt, float4* Av, float4* Bv) {
        const int text = t0 - 4 + wv * 64 + mt * 16 + j0;
        const bool okr = (text >= 0 && text < T_);
        const float* rowp = pose + (nrow0 + (okr ? text : 0)) * FIN_;
        #pragma unroll
        for (int s = 0; s < 5; ++s) {
            const int k0 = s * 32 + g8 * 8;
            const bool ok = okr && (k0 < FIN_);
            Av[s] = ok ? *(const float4*)(rowp + k0)     : make_float4(0.f, 0.f, 0.f, 0.f);
            Bv[s] = ok ? *(const float4*)(rowp + k0 + 4) : make_float4(0.f, 0.f, 0.f, 0.f);
        }
    };

    issue(0, pA, pB);
    #pragma unroll
    for (int mt = 0; mt < 4; ++mt) {
        // convert current tile to bf16 A-frags (waits on its loads)
        short8 af[5];
        #pragma unroll
        for (int s = 0; s < 5; ++s) {
            union { unsigned u[4]; short8 s8; } cvu;
            cvu.u[0] = pk2(pA[s].x, pA[s].y);
            cvu.u[1] = pk2(pA[s].z, pA[s].w);
            cvu.u[2] = pk2(pB[s].x, pB[s].y);
            cvu.u[3] = pk2(pB[s].z, pB[s].w);
            af[s] = cvu.s8;
        }
        // issue next tile's loads (hide latency under MFMA + z-write)
        if (mt < 3) issue(mt + 1, pA, pB);

        f32x4 acc0 = {0.f, 0.f, 0.f, 0.f};
        f32x4 acc1 = {0.f, 0.f, 0.f, 0.f};
        #pragma unroll
        for (int s = 0; s < 5; ++s) {
            acc0 = __builtin_amdgcn_mfma_f32_16x16x32_bf16(af[s], bfrag[s][0], acc0, 0, 0, 0);
            acc1 = __builtin_amdgcn_mfma_f32_16x16x32_bf16(af[s], bfrag[s][1], acc1, 0, 0, 0);
        }
        // D layout: col = lane&15, row = (lane>>4)*4 + reg
        #pragma unroll
        for (int r = 0; r < 4; ++r) {
            const int zrow = wv * 64 + mt * 16 + g8 * 4 + r;
            const int text = t0 - 4 + zrow;
            const bool okz = (text >= 0 && text < T_);
            zbuf[zrow * ZS_ + j0] = okz ? acc0[r] + b0n0 : 0.f;
            if (j0 < 11)
                zbuf[zrow * ZS_ + 16 + j0] = okz ? acc1[r] + b0n1 : 0.f;
        }
    }
    __syncthreads();

    // ---- Stage 2: temporal 9-tap mix + bias + leaky relu ----
    const int rows_out = min(TILE_, T_ - t0);
    float oacc[J_];
    if (tid < rows_out) {
        #pragma unroll
        for (int w = 0; w < V_; ++w)
            #pragma unroll
            for (int o2 = 0; o2 < 3; ++o2)
                oacc[w * 3 + o2] = cw[BT_OFF + o2];
        #pragma unroll
        for (int dd = 0; dd < KT_; ++dd) {
            union { f32x4 v4[7]; float f[28]; } zu;
            const f32x4* zp = (const f32x4*)&zbuf[(tid + dd) * ZS_];
            #pragma unroll
            for (int c = 0; c < 7; ++c) zu.v4[c] = zp[c];
            #pragma unroll
            for (int o = 0; o < 3; ++o) {
                #pragma unroll
                for (int o2 = 0; o2 < 3; ++o2) {
                    const float wt = cw[WT_OFF + o * 27 + o2 * 9 + dd];
                    #pragma unroll
                    for (int w = 0; w < V_; ++w)
                        oacc[w * 3 + o2] = fmaf(zu.f[w * 3 + o], wt, oacc[w * 3 + o2]);
                }
            }
        }
        #pragma unroll
        for (int j = 0; j < J_; ++j) oacc[j] = fmaxf(oacc[j], 0.01f * oacc[j]);
    }
    __syncthreads();
    // repack tight (stride 27) into zbuf for coalesced store
    if (tid < rows_out) {
        #pragma unroll
        for (int j = 0; j < J_; ++j) zbuf[tid * J_ + j] = oacc[j];
    }
    __syncthreads();

    const int total4 = (rows_out * J_) / 4;   // 1674 or 432
    float4* dst4 = (float4*)(out + (nrow0 + t0) * J_);
    const float4* src4 = (const float4*)zbuf;
    for (int idx = tid; idx < total4; idx += THREADS_)
        dst4[idx] = src4[idx];
}

extern "C" void kernel_launch(void* const* d_in, const int* in_sizes, int n_in,
                              void* d_out, int out_size, void* d_ws, size_t ws_size,
                              hipStream_t stream) {
    const float* pose = (const float*)d_in[0];
    const float* A    = (const float*)d_in[1];
    const float* Wg   = (const float*)d_in[2];
    const float* bg   = (const float*)d_in[3];
    const float* Wt   = (const float*)d_in[4];
    const float* bt   = (const float*)d_in[5];
    float* ws   = (float*)d_ws;
    float* outp = (float*)d_out;

    setup_weights<<<1, 256, 0, stream>>>(A, Wg, bg, Wt, bt, ws);
    fused_stgcn<<<N_ * NTILE_, THREADS_, 0, stream>>>(pose, ws, outp);
}

// Round 5
// 87.113 us; speedup vs baseline: 1.4709x; 1.0014x over previous
//
#include <hip/hip_runtime.h>

typedef short short8 __attribute__((ext_vector_type(8)));
typedef float f32x4  __attribute__((ext_vector_type(4)));

// Problem dims
constexpr int N_    = 256;
constexpr int T_    = 2048;
constexpr int V_    = 9;
constexpr int FIN_  = 144;      // K dim of stage-1 GEMM
constexpr int J_    = 27;       // output cols (w*3 + o)
constexpr int KT_   = 9;
constexpr int THREADS_ = 128;                    // 2 waves -> small blocks, phase diversity
constexpr int TILE_ = 120;                       // output rows per block
constexpr int NTILE_ = 18;                       // ceil(2048/120)
constexpr int ZROWS_ = 128;                      // z rows per block (TILE_+8)
constexpr int ZS_ = 28;                          // z row stride floats (conflict-free b128)
 // zbuf = 128*28*4 = 14336 B (repack 120*27*4=12960 B aliases it)

// ws layout (float units)
constexpr int BF_OFF_F = 0;      // B-frags: 5120 bf16 (2560 floats)
constexpr int B0_OFF   = 2560;   // B0[27]
constexpr int WT_OFF   = 2587;   // Wt[o][o2][dd] (81)
constexpr int BT_OFF   = 2668;   // b_tcn[3]

__device__ __forceinline__ unsigned short bf16_rne(float x) {
    unsigned u = __float_as_uint(x);
    u = (u + 0x7FFFu + ((u >> 16) & 1u)) >> 16;
    return (unsigned short)u;
}
__device__ __forceinline__ unsigned pk2(float a, float b) {
    return (unsigned)bf16_rne(a) | ((unsigned)bf16_rne(b) << 16);
}

__global__ void setup_weights(const float* __restrict__ A,
                              const float* __restrict__ Wg,
                              const float* __restrict__ bg,
                              const float* __restrict__ Wt_in,
                              const float* __restrict__ bt,
                              float* __restrict__ ws) {
    __shared__ float Wc[FIN_ * J_];   // [k=f][n=j]
    const int tid = threadIdx.x;
    for (int idx = tid; idx < FIN_ * J_; idx += 256) {
        const int f = idx / J_, j = idx % J_;
        const int v = f >> 4, c = f & 15;
        const int w = j / 3, o = j % 3;
        float s = 0.f;
        #pragma unroll
        for (int k = 0; k < 5; ++k)
            s += Wg[(k * 3 + o) * 16 + c] * A[(k * 9 + v) * 9 + w];
        Wc[idx] = s;
    }
    __syncthreads();
    // B-fragments for mfma_f32_16x16x32_bf16: elem e of lane: (k=s*32+(l>>4)*8+e, n=nt*16+(l&15))
    unsigned short* bfp = (unsigned short*)(ws + BF_OFF_F);
    for (int i = tid; i < 5120; i += 256) {
        const int e = i & 7, lane = (i >> 3) & 63, nt = (i >> 9) & 1, s = i >> 10;
        const int k = s * 32 + (lane >> 4) * 8 + e;
        const int n = nt * 16 + (lane & 15);
        const float val = (k < FIN_ && n < J_) ? Wc[k * J_ + n] : 0.f;
        bfp[i] = bf16_rne(val);
    }
    if (tid < J_) {
        const int w = tid / 3, o = tid % 3;
        float s = 0.f;
        #pragma unroll
        for (int k = 0; k < 5; ++k) {
            float cs = 0.f;
            #pragma unroll
            for (int v = 0; v < V_; ++v) cs += A[(k * 9 + v) * 9 + w];
            s += bg[k * 3 + o] * cs;
        }
        ws[B0_OFF + tid] = s;
    }
    // Wt[o][o2][dd] = W_tcn[(o2*3+o)*9 + (8-dd)]  (conv_transpose: flip + I/O swap)
    if (tid < 81) {
        const int o = tid / 27, r = tid % 27, o2 = r / 9, dd = r % 9;
        ws[WT_OFF + tid] = Wt_in[(o2 * 3 + o) * 9 + (8 - dd)];
    }
    if (tid < 3) ws[BT_OFF + tid] = bt[tid];
}

__global__ __launch_bounds__(THREADS_, 3) void fused_stgcn(const float* __restrict__ pose,
                                                           const float* __restrict__ cw,
                                                           float* __restrict__ out) {
    __shared__ __align__(16) float zbuf[ZROWS_ * ZS_];   // 14336 B

    const int tid  = threadIdx.x;
    const int bid  = blockIdx.x;
    const int nb   = bid / NTILE_;
    const int tile = bid % NTILE_;
    const int t0   = tile * TILE_;
    const int lane = tid & 63;
    const int wv   = tid >> 6;          // 0..1
    const int g8   = lane >> 4;
    const int j0   = lane & 15;

    // B-fragments -> registers (40 VGPRs), coalesced 16B loads (L2-resident ws)
    short8 bfrag[5][2];
    {
        const short8* bsrc = (const short8*)(cw + BF_OFF_F);
        #pragma unroll
        for (int s = 0; s < 5; ++s)
            #pragma unroll
            for (int nt = 0; nt < 2; ++nt)
                bfrag[s][nt] = bsrc[(s * 2 + nt) * 64 + lane];
    }
    const float b0n0 = cw[B0_OFF + j0];
    const float b0n1 = (j0 < 11) ? cw[B0_OFF + 16 + j0] : 0.f;

    // ---- Stage 1: per-wave; direct global->reg A-frags; 4 M-tiles of 16 rows; dbuf loads ----
    const size_t nrow0 = (size_t)nb * T_;

    auto issue = [&](int mt, float4* Av, float4* Bv) {
        const int text = t0 - 4 + wv * 64 + mt * 16 + j0;
        const bool okr = (text >= 0 && text < T_);
        const float* rowp = pose + (nrow0 + (okr ? text : 0)) * FIN_;
        #pragma unroll
        for (int s = 0; s < 5; ++s) {
            const int k0 = s * 32 + g8 * 8;
            const bool ok = okr && (k0 < FIN_);
            Av[s] = ok ? *(const float4*)(rowp + k0)     : make_float4(0.f, 0.f, 0.f, 0.f);
            Bv[s] = ok ? *(const float4*)(rowp + k0 + 4) : make_float4(0.f, 0.f, 0.f, 0.f);
        }
    };
    auto process = [&](int mt, const float4* Av, const float4* Bv) {
        short8 af[5];
        #pragma unroll
        for (int s = 0; s < 5; ++s) {
            union { unsigned u[4]; short8 s8; } cvu;
            cvu.u[0] = pk2(Av[s].x, Av[s].y);
            cvu.u[1] = pk2(Av[s].z, Av[s].w);
            cvu.u[2] = pk2(Bv[s].x, Bv[s].y);
            cvu.u[3] = pk2(Bv[s].z, Bv[s].w);
            af[s] = cvu.s8;
        }
        f32x4 acc0 = {0.f, 0.f, 0.f, 0.f};
        f32x4 acc1 = {0.f, 0.f, 0.f, 0.f};
        #pragma unroll
        for (int s = 0; s < 5; ++s) {
            acc0 = __builtin_amdgcn_mfma_f32_16x16x32_bf16(af[s], bfrag[s][0], acc0, 0, 0, 0);
            acc1 = __builtin_amdgcn_mfma_f32_16x16x32_bf16(af[s], bfrag[s][1], acc1, 0, 0, 0);
        }
        // D layout: col = lane&15, row = (lane>>4)*4 + reg
        #pragma unroll
        for (int r = 0; r < 4; ++r) {
            const int zrow = wv * 64 + mt * 16 + g8 * 4 + r;
            const int text = t0 - 4 + zrow;
            const bool okz = (text >= 0 && text < T_);
            zbuf[zrow * ZS_ + j0] = okz ? acc0[r] + b0n0 : 0.f;
            if (j0 < 11)
                zbuf[zrow * ZS_ + 16 + j0] = okz ? acc1[r] + b0n1 : 0.f;
        }
    };

    float4 A0[5], B0v[5], A1[5], B1[5];
    issue(0, A0, B0v);
    issue(1, A1, B1);          // both buffers in flight before first convert
    process(0, A0, B0v);
    issue(2, A0, B0v);
    process(1, A1, B1);
    issue(3, A1, B1);
    process(2, A0, B0v);
    process(3, A1, B1);
    __syncthreads();

    // ---- Stage 2: temporal 9-tap mix + bias + leaky relu ----
    const int rows_out = min(TILE_, T_ - t0);
    float oacc[J_];
    if (tid < rows_out) {
        #pragma unroll
        for (int w = 0; w < V_; ++w)
            #pragma unroll
            for (int o2 = 0; o2 < 3; ++o2)
                oacc[w * 3 + o2] = cw[BT_OFF + o2];
        #pragma unroll
        for (int dd = 0; dd < KT_; ++dd) {
            union { f32x4 v4[7]; float f[28]; } zu;
            const f32x4* zp = (const f32x4*)&zbuf[(tid + dd) * ZS_];
            #pragma unroll
            for (int c = 0; c < 7; ++c) zu.v4[c] = zp[c];
            #pragma unroll
            for (int o = 0; o < 3; ++o) {
                #pragma unroll
                for (int o2 = 0; o2 < 3; ++o2) {
                    const float wt = cw[WT_OFF + o * 27 + o2 * 9 + dd];
                    #pragma unroll
                    for (int w = 0; w < V_; ++w)
                        oacc[w * 3 + o2] = fmaf(zu.f[w * 3 + o], wt, oacc[w * 3 + o2]);
                }
            }
        }
        #pragma unroll
        for (int j = 0; j < J_; ++j) oacc[j] = fmaxf(oacc[j], 0.01f * oacc[j]);
    }
    __syncthreads();
    // repack tight (stride 27) into zbuf for coalesced store (12960 B <= zbuf)
    if (tid < rows_out) {
        #pragma unroll
        for (int j = 0; j < J_; ++j) zbuf[tid * J_ + j] = oacc[j];
    }
    __syncthreads();

    const int total4 = (rows_out * J_) / 4;   // 810 or 54
    float4* dst4 = (float4*)(out + (nrow0 + t0) * J_);
    const float4* src4 = (const float4*)zbuf;
    for (int idx = tid; idx < total4; idx += THREADS_)
        dst4[idx] = src4[idx];
}

extern "C" void kernel_launch(void* const* d_in, const int* in_sizes, int n_in,
                              void* d_out, int out_size, void* d_ws, size_t ws_size,
                              hipStream_t stream) {
    const float* pose = (const float*)d_in[0];
    const float* A    = (const float*)d_in[1];
    const float* Wg   = (const float*)d_in[2];
    const float* bg   = (const float*)d_in[3];
    const float* Wt   = (const float*)d_in[4];
    const float* bt   = (const float*)d_in[5];
    float* ws   = (float*)d_ws;
    float* outp = (float*)d_out;

    setup_weights<<<1, 256, 0, stream>>>(A, Wg, bg, Wt, bt, ws);
    fused_stgcn<<<N_ * NTILE_, THREADS_, 0, stream>>>(pose, ws, outp);
}